// Round 1
// baseline (573.920 us; speedup 1.0000x reference)
//
#include <hip/hip_runtime.h>
#include <hip/hip_bf16.h>

#define C_DIM 1024
#define HW    196
#define NWAY  64
#define HALF_M 98
#define M_PAD 112          // 7 * 16
#define MT    7            // m-tiles (16 rows each) per block
#define BK    64           // K per staging step
#define LDK   72           // BK + 8 bf16 pad (row stride, breaks bank conflicts)
#define N_TOT (512 * 196)

typedef short bf16x8 __attribute__((ext_vector_type(8)));
typedef float floatx4 __attribute__((ext_vector_type(4)));

__device__ __forceinline__ unsigned short f2bf(float x) {
    unsigned int u = __float_as_uint(x);
    u += 0x7fffu + ((u >> 16) & 1u);          // round-to-nearest-even
    return (unsigned short)(u >> 16);
}

__device__ __forceinline__ bf16x8 pack8(const float v[8]) {
    bf16x8 r;
#pragma unroll
    for (int i = 0; i < 8; ++i) r[i] = (short)f2bf(v[i]);
    return r;
}

__global__ __launch_bounds__(256) void dfmn_main(
    const float* __restrict__ qf, const int* __restrict__ labels,
    const float* __restrict__ protos, const int* __restrict__ indices,
    float* __restrict__ out)
{
    // 25480 B overlay: staging (a_lds 112x72 + b_lds 64x72 bf16 = 25344 B)
    // vs epilogue logits (98 x 65 fp32 = 25480 B)
    __shared__ __align__(16) float smem[6370];
    __shared__ float pn_lds[NWAY];
    __shared__ float wsum[4];

    const int t    = threadIdx.x;
    const int lane = t & 63;
    const int wave = t >> 6;

    // XCD swizzle: both halves of one image land on the same XCD (round-robin %8)
    const int x    = blockIdx.x;
    const int xcd  = x & 7;
    const int grp  = x >> 3;
    const int half = grp & 1;
    const int b    = (grp >> 1) * 8 + xcd;     // image index 0..511
    const int hw0  = half * HALF_M;

    unsigned short* a_lds = (unsigned short*)smem;     // [M_PAD][LDK]
    unsigned short* b_lds = a_lds + M_PAD * LDK;       // [NWAY][LDK]
    float* logits = smem;                              // [HALF_M][65]

    // ---- prototype squared norms pn[64] (from L2-cached prototypes) ----
    {
        const int cls = t >> 2, part = t & 3;
        const int gid = indices[cls];
        const float4* prow = (const float4*)(protos + (size_t)gid * C_DIM) + part * 64;
        float s = 0.f;
#pragma unroll 4
        for (int i = 0; i < 64; ++i) {
            float4 v = prow[i];
            s += v.x * v.x + v.y * v.y + v.z * v.z + v.w * v.w;
        }
        smem[t] = s;
    }
    __syncthreads();
    if (t < NWAY) pn_lds[t] = smem[4 * t] + smem[4 * t + 1] + smem[4 * t + 2] + smem[4 * t + 3];
    __syncthreads();

    // ---- B staging constants (gather rows via indices, hoisted) ----
    const int boct = t & 7;
    const int bcls = t >> 3;  // 0..31
    const float* bsrc0 = protos + (size_t)indices[bcls] * C_DIM + boct * 8;
    const float* bsrc1 = protos + (size_t)indices[bcls + 32] * C_DIM + boct * 8;

    const size_t img_off = (size_t)b * (C_DIM * HW);

    floatx4 acc[MT];
#pragma unroll
    for (int i = 0; i < MT; ++i) acc[i] = (floatx4)0.f;

    const int frm  = lane & 15;
    const int quad = lane >> 4;
    const unsigned short* bfrag_base = b_lds + (wave * 16 + frm) * LDK + quad * 8;

    for (int k0 = 0; k0 < C_DIM; k0 += BK) {
        // ---- stage A: transpose fp32 [c][hw] -> bf16 LDS [hw][c] ----
#pragma unroll
        for (int it = 0; it < 4; ++it) {
            int idx = it * 256 + t;
            if (idx < M_PAD * 8) {
                int lr  = idx % M_PAD;    // local pixel row (coalesced across lanes)
                int oct = idx / M_PAD;    // which 8-channel octet
                float v[8];
                if (lr < HALF_M) {
                    const float* src = qf + img_off + (size_t)(k0 + oct * 8) * HW + hw0 + lr;
#pragma unroll
                    for (int j = 0; j < 8; ++j) v[j] = src[(size_t)j * HW];
                } else {
#pragma unroll
                    for (int j = 0; j < 8; ++j) v[j] = 0.f;  // zero pad rows 98..111
                }
                *(bf16x8*)(a_lds + lr * LDK + oct * 8) = pack8(v);
            }
        }
        // ---- stage B: protos fp32 -> bf16 LDS [cls][c] ----
        {
            float4 x0 = *(const float4*)(bsrc0 + k0);
            float4 x1 = *(const float4*)(bsrc0 + k0 + 4);
            float v[8] = {x0.x, x0.y, x0.z, x0.w, x1.x, x1.y, x1.z, x1.w};
            *(bf16x8*)(b_lds + bcls * LDK + boct * 8) = pack8(v);
            float4 y0 = *(const float4*)(bsrc1 + k0);
            float4 y1 = *(const float4*)(bsrc1 + k0 + 4);
            float w[8] = {y0.x, y0.y, y0.z, y0.w, y1.x, y1.y, y1.z, y1.w};
            *(bf16x8*)(b_lds + (bcls + 32) * LDK + boct * 8) = pack8(w);
        }
        __syncthreads();
        // ---- MFMA: wave = one 16-class n-tile x all 7 m-tiles ----
#pragma unroll
        for (int kk = 0; kk < 2; ++kk) {
            bf16x8 bv = *(const bf16x8*)(bfrag_base + kk * 32);
#pragma unroll
            for (int mt = 0; mt < MT; ++mt) {
                bf16x8 av = *(const bf16x8*)(a_lds + (mt * 16 + frm) * LDK + quad * 8 + kk * 32);
                acc[mt] = __builtin_amdgcn_mfma_f32_16x16x32_bf16(av, bv, acc[mt], 0, 0, 0);
            }
        }
        __syncthreads();
    }

    // ---- epilogue: logits -> LDS, per-row softmax loss ----
    {
        const int colg = wave * 16 + frm;
        const float pnc = pn_lds[colg];
#pragma unroll
        for (int mt = 0; mt < MT; ++mt) {
#pragma unroll
            for (int r = 0; r < 4; ++r) {
                int row = mt * 16 + quad * 4 + r;  // C/D: row=(lane>>4)*4+reg, col=lane&15
                if (row < HALF_M) logits[row * 65 + colg] = 2.0f * acc[mt][r] - pnc;
            }
        }
    }
    __syncthreads();

    float partial = 0.f;
    if (t < HALF_M) {
        const float* srow = logits + t * 65;
        float mx = -1e30f;
#pragma unroll 8
        for (int c = 0; c < NWAY; ++c) mx = fmaxf(mx, srow[c]);
        float sum = 0.f;
#pragma unroll 8
        for (int c = 0; c < NWAY; ++c) sum += __expf(srow[c] - mx);
        const float lse = mx + __logf(sum);
        partial = (lse - srow[labels[b]]) * (1.0f / (float)N_TOT);
    }
#pragma unroll
    for (int off = 32; off > 0; off >>= 1) partial += __shfl_down(partial, off, 64);
    if (lane == 0) wsum[wave] = partial;
    __syncthreads();
    if (t == 0) atomicAdd(out, wsum[0] + wsum[1] + wsum[2] + wsum[3]);
}

extern "C" void kernel_launch(void* const* d_in, const int* in_sizes, int n_in,
                              void* d_out, int out_size, void* d_ws, size_t ws_size,
                              hipStream_t stream) {
    const float* qf      = (const float*)d_in[0];
    const int*   labels  = (const int*)d_in[1];
    const float* protos  = (const float*)d_in[2];
    const int*   indices = (const int*)d_in[3];
    // d_in[4] = n_way (scalar, fixed 64)

    hipMemsetAsync(d_out, 0, sizeof(float), stream);  // atomicAdd target
    hipLaunchKernelGGL(dfmn_main, dim3(1024), dim3(256), 0, stream,
                       qf, labels, protos, indices, (float*)d_out);
}

// Round 2
// 559.669 us; speedup vs baseline: 1.0255x; 1.0255x over previous
//
#include <hip/hip_runtime.h>
#include <hip/hip_bf16.h>

#define C_DIM 1024
#define HW    196
#define NWAY  64
#define BK    64
#define KSTEPS (C_DIM / BK)   // 16
#define LDB   72              // b_lds row stride (shorts); 144 B, 16B-aligned
#define N_TOT (512 * 196)

typedef short bf16x8 __attribute__((ext_vector_type(8)));
typedef float floatx4 __attribute__((ext_vector_type(4)));
typedef unsigned int u32;

__device__ __forceinline__ unsigned short f2bf(float x) {
    u32 u = __float_as_uint(x);
    u += 0x7fffu + ((u >> 16) & 1u);   // RNE
    return (unsigned short)(u >> 16);
}

__device__ __forceinline__ bf16x8 pack8(const float v[8]) {
    bf16x8 r;
#pragma unroll
    for (int i = 0; i < 8; ++i) r[i] = (short)f2bf(v[i]);
    return r;
}

// async global->LDS, 16 B per lane; lds dest = wave-uniform base + lane*16
__device__ __forceinline__ void gload16(const float* g, float* l) {
    __builtin_amdgcn_global_load_lds(
        (const __attribute__((address_space(1))) u32*)g,
        (__attribute__((address_space(3))) u32*)l, 16, 0, 0);
}

__global__ __launch_bounds__(256, 2) void dfmn_main(
    const float* __restrict__ qf, const int* __restrict__ labels,
    const float* __restrict__ protos, const int* __restrict__ indices,
    float* __restrict__ out)
{
    __shared__ __align__(16) float a_lds[BK * HW];                 // 50176 B fp32 [ch][px]
    __shared__ __align__(16) unsigned short b_lds[NWAY * LDB];     // 9216 B bf16 [cls][ch]
    __shared__ float pn_lds[NWAY];
    __shared__ float wsum[4];

    const int t    = threadIdx.x;
    const int lane = t & 63;
    const int wave = t >> 6;
    const int frm  = lane & 15;
    const int q    = lane >> 4;
    const int b    = blockIdx.x;                 // one image per block

    // ---- prototype squared norms (exact fp32, protos are L2-resident) ----
    {
        const int cls = t >> 2, part = t & 3;
        const float* prow = protos + (size_t)indices[cls] * C_DIM + part * 256;
        float s = 0.f;
#pragma unroll 4
        for (int i = 0; i < 64; ++i) {
            float4 v = ((const float4*)prow)[i];
            s += v.x * v.x + v.y * v.y + v.z * v.z + v.w * v.w;
        }
        a_lds[t] = s;
    }
    __syncthreads();
    if (t < NWAY) pn_lds[t] = a_lds[4*t] + a_lds[4*t+1] + a_lds[4*t+2] + a_lds[4*t+3];
    __syncthreads();

    // ---- B staging pointers (2 items/thread: 512 = 64 cls x 8 octets) ----
    const int soct = t & 7;
    const float* pb0 = protos + (size_t)indices[t >> 3] * C_DIM + soct * 8;
    const float* pb1 = protos + (size_t)indices[(t + 256) >> 3] * C_DIM + soct * 8;
    unsigned short* bw0 = &b_lds[(t >> 3) * LDB + soct * 8];
    unsigned short* bw1 = &b_lds[((t + 256) >> 3) * LDB + soct * 8];

    const float* qf_img = qf + (size_t)b * (C_DIM * HW);

    // wave -> m-tiles: {0..3},{4..6},{7..9},{10..12}  (13 tiles cover 196 rows + pad)
    const int mbase = (wave == 0) ? 0 : 4 + 3 * (wave - 1);
    const int mcnt  = (wave == 0) ? 4 : 3;

    floatx4 acc[4][4];
#pragma unroll
    for (int i = 0; i < 4; ++i)
#pragma unroll
        for (int n = 0; n < 4; ++n) acc[i][n] = (floatx4)0.f;

    for (int ks = 0; ks < KSTEPS; ++ks) {
        const int k0 = ks * BK;
        const float* tile = qf_img + (size_t)k0 * HW;  // 64*196 floats, contiguous

        // ---- A: async global->LDS, 49 chunks of 1 KB, round-robin over waves ----
        for (int c = wave; c < 49; c += 4)
            gload16(tile + c * 256 + lane * 4, a_lds + c * 256);

        // ---- B: protos fp32 -> bf16 LDS [cls][ch] ----
        {
            float4 x0 = *(const float4*)(pb0 + k0);
            float4 x1 = *(const float4*)(pb0 + k0 + 4);
            float v[8] = {x0.x, x0.y, x0.z, x0.w, x1.x, x1.y, x1.z, x1.w};
            *(bf16x8*)bw0 = pack8(v);
            float4 y0 = *(const float4*)(pb1 + k0);
            float4 y1 = *(const float4*)(pb1 + k0 + 4);
            float w[8] = {y0.x, y0.y, y0.z, y0.w, y1.x, y1.y, y1.z, y1.w};
            *(bf16x8*)bw1 = pack8(w);
        }
        __syncthreads();

        // ---- MFMA: wave owns its m-tiles x all 4 n-tiles ----
#pragma unroll
        for (int kk = 0; kk < 2; ++kk) {
            const unsigned short* bb = &b_lds[frm * LDB + kk * 32 + q * 8];
            bf16x8 bv0 = *(const bf16x8*)(bb + 0 * 16 * LDB);
            bf16x8 bv1 = *(const bf16x8*)(bb + 1 * 16 * LDB);
            bf16x8 bv2 = *(const bf16x8*)(bb + 2 * 16 * LDB);
            bf16x8 bv3 = *(const bf16x8*)(bb + 3 * 16 * LDB);
            const float* ak = a_lds + (kk * 32 + q * 8) * HW + frm;
#pragma unroll
            for (int i = 0; i < 4; ++i) {
                if (i < mcnt) {
                    const float* ap = ak + (mbase + i) * 16;
                    float av[8];
#pragma unroll
                    for (int j = 0; j < 8; ++j) av[j] = ap[(size_t)j * HW];
                    bf16x8 a8 = pack8(av);
                    acc[i][0] = __builtin_amdgcn_mfma_f32_16x16x32_bf16(a8, bv0, acc[i][0], 0, 0, 0);
                    acc[i][1] = __builtin_amdgcn_mfma_f32_16x16x32_bf16(a8, bv1, acc[i][1], 0, 0, 0);
                    acc[i][2] = __builtin_amdgcn_mfma_f32_16x16x32_bf16(a8, bv2, acc[i][2], 0, 0, 0);
                    acc[i][3] = __builtin_amdgcn_mfma_f32_16x16x32_bf16(a8, bv3, acc[i][3], 0, 0, 0);
                }
            }
        }
        __syncthreads();
    }

    // ---- epilogue: softmax-loss in registers (C/D: col=lane&15, row=q*4+r) ----
    float pnr[4];
#pragma unroll
    for (int n = 0; n < 4; ++n) pnr[n] = pn_lds[n * 16 + frm];
    const int L   = labels[b];
    const int ntL = L >> 4;
    const int fL  = L & 15;

    float partial = 0.f;
#pragma unroll
    for (int i = 0; i < 4; ++i) {
        if (i < mcnt) {
            const int mt = mbase + i;
#pragma unroll
            for (int r = 0; r < 4; ++r) {
                float l0 = 2.f * acc[i][0][r] - pnr[0];
                float l1 = 2.f * acc[i][1][r] - pnr[1];
                float l2 = 2.f * acc[i][2][r] - pnr[2];
                float l3 = 2.f * acc[i][3][r] - pnr[3];
                float mx = fmaxf(fmaxf(l0, l1), fmaxf(l2, l3));
                mx = fmaxf(mx, __shfl_xor(mx, 1));
                mx = fmaxf(mx, __shfl_xor(mx, 2));
                mx = fmaxf(mx, __shfl_xor(mx, 4));
                mx = fmaxf(mx, __shfl_xor(mx, 8));
                float s = __expf(l0 - mx) + __expf(l1 - mx) + __expf(l2 - mx) + __expf(l3 - mx);
                s += __shfl_xor(s, 1);
                s += __shfl_xor(s, 2);
                s += __shfl_xor(s, 4);
                s += __shfl_xor(s, 8);
                float lse = mx + __logf(s);
                float lL = (ntL == 0) ? l0 : (ntL == 1) ? l1 : (ntL == 2) ? l2 : l3;
                lL = __shfl(lL, (lane & 48) + fL);   // broadcast label column within 16-group
                const int px = mt * 16 + q * 4 + r;
                if (px < HW) partial += (lse - lL);
            }
        }
    }
    partial *= (1.f / 16.f) * (1.f / (float)N_TOT);  // each row replicated across 16 lanes

#pragma unroll
    for (int off = 32; off > 0; off >>= 1) partial += __shfl_down(partial, off, 64);
    if (lane == 0) wsum[wave] = partial;
    __syncthreads();
    if (t == 0) atomicAdd(out, wsum[0] + wsum[1] + wsum[2] + wsum[3]);
}

extern "C" void kernel_launch(void* const* d_in, const int* in_sizes, int n_in,
                              void* d_out, int out_size, void* d_ws, size_t ws_size,
                              hipStream_t stream) {
    const float* qf      = (const float*)d_in[0];
    const int*   labels  = (const int*)d_in[1];
    const float* protos  = (const float*)d_in[2];
    const int*   indices = (const int*)d_in[3];

    hipMemsetAsync(d_out, 0, sizeof(float), stream);
    hipLaunchKernelGGL(dfmn_main, dim3(512), dim3(256), 0, stream,
                       qf, labels, protos, indices, (float*)d_out);
}

// Round 3
// 557.123 us; speedup vs baseline: 1.0301x; 1.0046x over previous
//
#include <hip/hip_runtime.h>
#include <hip/hip_bf16.h>

#define C_DIM 1024
#define HW    196
#define NWAY  64
#define BK    32
#define KSTEPS (C_DIM / BK)      // 32
#define AFLOATS (BK * HW)        // 6272 floats = 25088 B per buffer
#define LDB   40                 // b_lds row stride in shorts (80 B, 16B-aligned rows)
#define N_TOT (512 * 196)

typedef short bf16x8 __attribute__((ext_vector_type(8)));
typedef float floatx4 __attribute__((ext_vector_type(4)));
typedef unsigned int u32;

__device__ __forceinline__ unsigned short f2bf(float x) {
    u32 u = __float_as_uint(x);
    u += 0x7fffu + ((u >> 16) & 1u);   // RNE
    return (unsigned short)(u >> 16);
}

__device__ __forceinline__ bf16x8 pack8(const float v[8]) {
    bf16x8 r;
#pragma unroll
    for (int i = 0; i < 8; ++i) r[i] = (short)f2bf(v[i]);
    return r;
}

// async global->LDS, 16 B per lane; LDS dest = wave-uniform base + lane*16
__device__ __forceinline__ void gload16(const float* g, float* l) {
    __builtin_amdgcn_global_load_lds(
        (const __attribute__((address_space(1))) u32*)g,
        (__attribute__((address_space(3))) u32*)l, 16, 0, 0);
}

// Stage k-step: B global loads FIRST (so their waitcnt doesn't drain the async
// queue), then 25088 B of A via async global->LDS (24 full 1KB chunks + one
// 512 B half chunk), then pack+write B.
__device__ __forceinline__ void prefetch(const float* qtile, const float* pBk,
                                         float* abuf, unsigned short* bdst,
                                         int wave, int lane) {
    float4 x0 = *(const float4*)(pBk);
    float4 x1 = *(const float4*)(pBk + 4);
#pragma unroll
    for (int i = 0; i < 6; ++i) {
        const int c = i * 4 + wave;           // 0..23 round-robin over waves
        gload16(qtile + c * 256 + lane * 4, abuf + c * 256);
    }
    if (wave == 0 && lane < 32)               // trailing 512 B (exec-masked)
        gload16(qtile + 24 * 256 + lane * 4, abuf + 24 * 256);
    float v[8] = {x0.x, x0.y, x0.z, x0.w, x1.x, x1.y, x1.z, x1.w};
    *(bf16x8*)bdst = pack8(v);
}

__device__ __forceinline__ void kcompute(const float* abuf, const unsigned short* bbuf,
                                         floatx4 acc[4][4], int mbase, int mcnt,
                                         int frm, int q) {
    const unsigned short* bb = bbuf + frm * LDB + q * 8;
    bf16x8 bv[4];
#pragma unroll
    for (int n = 0; n < 4; ++n) bv[n] = *(const bf16x8*)(bb + n * 16 * LDB);
    const float* ak = abuf + (q * 8) * HW + frm;
#pragma unroll
    for (int i = 0; i < 4; ++i) {
        if (i < mcnt) {
            const float* ap = ak + (mbase + i) * 16;
            float av[8];
#pragma unroll
            for (int j = 0; j < 8; ++j) av[j] = ap[(size_t)j * HW];
            bf16x8 a8 = pack8(av);
#pragma unroll
            for (int n = 0; n < 4; ++n)
                acc[i][n] = __builtin_amdgcn_mfma_f32_16x16x32_bf16(a8, bv[n], acc[i][n], 0, 0, 0);
        }
    }
}

__global__ __launch_bounds__(256, 2) void dfmn_main(
    const float* __restrict__ qf, const int* __restrict__ labels,
    const float* __restrict__ protos, const int* __restrict__ indices,
    float* __restrict__ out)
{
    __shared__ __align__(16) float a_lds[2][AFLOATS];              // 2 x 25088 B
    __shared__ __align__(16) unsigned short b_lds[2][NWAY * LDB];  // 2 x 5120 B
    __shared__ float pn_lds[NWAY];
    __shared__ float wsum[4];

    const int t    = threadIdx.x;
    const int lane = t & 63;
    const int wave = t >> 6;
    const int frm  = lane & 15;
    const int q    = lane >> 4;
    const int b    = blockIdx.x;               // one image per block

    // ---- prototype squared norms (exact fp32; protos are L2-resident) ----
    {
        const int cls = t >> 2, part = t & 3;
        const float* prow = protos + (size_t)indices[cls] * C_DIM + part * 256;
        float s = 0.f;
#pragma unroll 4
        for (int i = 0; i < 64; ++i) {
            float4 v = ((const float4*)prow)[i];
            s += v.x * v.x + v.y * v.y + v.z * v.z + v.w * v.w;
        }
        a_lds[0][t] = s;
    }
    __syncthreads();
    if (t < NWAY)
        pn_lds[t] = a_lds[0][4*t] + a_lds[0][4*t+1] + a_lds[0][4*t+2] + a_lds[0][4*t+3];
    __syncthreads();

    const float* qf_img = qf + (size_t)b * (C_DIM * HW);
    const float* pB = protos + (size_t)indices[t >> 2] * C_DIM + (t & 3) * 8;
    unsigned short* bd0 = &b_lds[0][(t >> 2) * LDB + (t & 3) * 8];
    unsigned short* bd1 = &b_lds[1][(t >> 2) * LDB + (t & 3) * 8];

    // wave -> m-tiles: {0..3},{4..6},{7..9},{10..12}
    const int mbase = (wave == 0) ? 0 : 4 + 3 * (wave - 1);
    const int mcnt  = (wave == 0) ? 4 : 3;

    floatx4 acc[4][4];
#pragma unroll
    for (int i = 0; i < 4; ++i)
#pragma unroll
        for (int n = 0; n < 4; ++n) acc[i][n] = (floatx4)0.f;

    // ---- pipelined K-loop: prefetch(ks+1) -> compute(ks) -> barrier ----
    prefetch(qf_img, pB, a_lds[0], bd0, wave, lane);
    __syncthreads();

    for (int ks = 0; ks < KSTEPS; ks += 2) {
        if (ks + 1 < KSTEPS)
            prefetch(qf_img + (size_t)(ks + 1) * AFLOATS, pB + (ks + 1) * BK,
                     a_lds[1], bd1, wave, lane);
        kcompute(a_lds[0], b_lds[0], acc, mbase, mcnt, frm, q);
        __syncthreads();
        if (ks + 2 < KSTEPS)
            prefetch(qf_img + (size_t)(ks + 2) * AFLOATS, pB + (ks + 2) * BK,
                     a_lds[0], bd0, wave, lane);
        kcompute(a_lds[1], b_lds[1], acc, mbase, mcnt, frm, q);
        __syncthreads();
    }

    // ---- epilogue: softmax-loss in registers (C/D: col=lane&15, row=q*4+r) ----
    float pnr[4];
#pragma unroll
    for (int n = 0; n < 4; ++n) pnr[n] = pn_lds[n * 16 + frm];
    const int L   = labels[b];
    const int ntL = L >> 4;
    const int fL  = L & 15;

    float partial = 0.f;
#pragma unroll
    for (int i = 0; i < 4; ++i) {
        if (i < mcnt) {
            const int mt = mbase + i;
#pragma unroll
            for (int r = 0; r < 4; ++r) {
                float l0 = 2.f * acc[i][0][r] - pnr[0];
                float l1 = 2.f * acc[i][1][r] - pnr[1];
                float l2 = 2.f * acc[i][2][r] - pnr[2];
                float l3 = 2.f * acc[i][3][r] - pnr[3];
                float mx = fmaxf(fmaxf(l0, l1), fmaxf(l2, l3));
                mx = fmaxf(mx, __shfl_xor(mx, 1));
                mx = fmaxf(mx, __shfl_xor(mx, 2));
                mx = fmaxf(mx, __shfl_xor(mx, 4));
                mx = fmaxf(mx, __shfl_xor(mx, 8));
                float s = __expf(l0 - mx) + __expf(l1 - mx) + __expf(l2 - mx) + __expf(l3 - mx);
                s += __shfl_xor(s, 1);
                s += __shfl_xor(s, 2);
                s += __shfl_xor(s, 4);
                s += __shfl_xor(s, 8);
                float lse = mx + __logf(s);
                float lL = (ntL == 0) ? l0 : (ntL == 1) ? l1 : (ntL == 2) ? l2 : l3;
                lL = __shfl(lL, (lane & 48) + fL);   // broadcast label column
                const int px = mt * 16 + q * 4 + r;
                if (px < HW) partial += (lse - lL);
            }
        }
    }
    partial *= (1.f / 16.f) * (1.f / (float)N_TOT);  // rows replicated across 16 lanes

#pragma unroll
    for (int off = 32; off > 0; off >>= 1) partial += __shfl_down(partial, off, 64);
    if (lane == 0) wsum[wave] = partial;
    __syncthreads();
    if (t == 0) atomicAdd(out, wsum[0] + wsum[1] + wsum[2] + wsum[3]);
}

extern "C" void kernel_launch(void* const* d_in, const int* in_sizes, int n_in,
                              void* d_out, int out_size, void* d_ws, size_t ws_size,
                              hipStream_t stream) {
    const float* qf      = (const float*)d_in[0];
    const int*   labels  = (const int*)d_in[1];
    const float* protos  = (const float*)d_in[2];
    const int*   indices = (const int*)d_in[3];

    hipMemsetAsync(d_out, 0, sizeof(float), stream);
    hipLaunchKernelGGL(dfmn_main, dim3(512), dim3(256), 0, stream,
                       qf, labels, protos, indices, (float*)d_out);
}